// Round 5
// baseline (523.168 us; speedup 1.0000x reference)
//
#include <hip/hip_runtime.h>
#include <cstddef>

#define IN_F 256
#define OUT_F 128
#define SCAN_CHUNK 1024
#define RANGES 16
#define SCHUNKS 512
#define NXCD 8

// ---------------- GEMM: support = X @ W  (fp32, vector FMA) ----------------
// BM=64 rows, BN=128 cols (=OUT_F), BK=32. 256 threads; each thread 8x4 outputs.
__global__ __launch_bounds__(256) void gemm_kernel(const float* __restrict__ X,
                                                   const float* __restrict__ W,
                                                   float* __restrict__ S,
                                                   int nrows) {
    __shared__ float Xs[32][68];    // [k][row], stride 68: b128-aligned (272B)
    __shared__ float Ws[32][128];   // [k][col]
    const int t = threadIdx.x;
    const int bm = blockIdx.x * 64;
    const int tr = (t >> 5) * 8;
    const int tc = (t & 31) * 4;
    float acc[8][4] = {};

    for (int kt = 0; kt < IN_F; kt += 32) {
#pragma unroll
        for (int l = 0; l < 2; ++l) {
            const int idx = t + l * 256;
            const int r = idx >> 3;
            const int k4 = idx & 7;
            int rr = bm + r; if (rr >= nrows) rr = nrows - 1;
            const float4 v = *reinterpret_cast<const float4*>(
                &X[(size_t)rr * IN_F + kt + k4 * 4]);
            Xs[k4 * 4 + 0][r] = v.x;
            Xs[k4 * 4 + 1][r] = v.y;
            Xs[k4 * 4 + 2][r] = v.z;
            Xs[k4 * 4 + 3][r] = v.w;
        }
#pragma unroll
        for (int l = 0; l < 4; ++l) {
            const int q = t + l * 256;
            const int k = q >> 5;
            const int c = (q & 31) * 4;
            *reinterpret_cast<float4*>(&Ws[k][c]) =
                *reinterpret_cast<const float4*>(&W[(size_t)(kt + k) * OUT_F + c]);
        }
        __syncthreads();
#pragma unroll 4
        for (int kk = 0; kk < 32; ++kk) {
            const float4 x0 = *reinterpret_cast<const float4*>(&Xs[kk][tr]);
            const float4 x1 = *reinterpret_cast<const float4*>(&Xs[kk][tr + 4]);
            const float4 wv = *reinterpret_cast<const float4*>(&Ws[kk][tc]);
            const float xr8[8] = {x0.x, x0.y, x0.z, x0.w, x1.x, x1.y, x1.z, x1.w};
#pragma unroll
            for (int j = 0; j < 8; ++j) {
                acc[j][0] += xr8[j] * wv.x;
                acc[j][1] += xr8[j] * wv.y;
                acc[j][2] += xr8[j] * wv.z;
                acc[j][3] += xr8[j] * wv.w;
            }
        }
        __syncthreads();
    }
#pragma unroll
    for (int j = 0; j < 8; ++j) {
        const int row = bm + tr + j;
        if (row < nrows) {
            *reinterpret_cast<float4*>(&S[(size_t)row * OUT_F + tc]) =
                make_float4(acc[j][0], acc[j][1], acc[j][2], acc[j][3]);
        }
    }
}

// ---------------- CSR build ----------------
__global__ void hist_kernel(const int* __restrict__ dst, int* __restrict__ counts, int E) {
    int i = blockIdx.x * blockDim.x + threadIdx.x;
    const int stride = gridDim.x * blockDim.x;
    for (; i < E; i += stride) atomicAdd(&counts[dst[i]], 1);
}

__global__ __launch_bounds__(256) void scan1_kernel(const int* __restrict__ counts,
                                                    int* __restrict__ off,
                                                    int* __restrict__ bsums, int n) {
    __shared__ int sd[256];
    const int t = threadIdx.x;
    const int base = blockIdx.x * SCAN_CHUNK + t * 4;
    int c[4]; int s = 0;
#pragma unroll
    for (int j = 0; j < 4; ++j) {
        c[j] = (base + j < n) ? counts[base + j] : 0;
        s += c[j];
    }
    sd[t] = s;
    __syncthreads();
    for (int d = 1; d < 256; d <<= 1) {
        int v = (t >= d) ? sd[t - d] : 0;
        __syncthreads();
        sd[t] += v;
        __syncthreads();
    }
    int run = sd[t] - s;
#pragma unroll
    for (int j = 0; j < 4; ++j) {
        if (base + j < n) off[base + j] = run;
        run += c[j];
    }
    if (t == 255) bsums[blockIdx.x] = sd[255];
}

__global__ __launch_bounds__(256) void scan2_kernel(int* __restrict__ bsums, int nb) {
    __shared__ int sd[256];
    const int t = threadIdx.x;
    const int v = (t < nb) ? bsums[t] : 0;
    sd[t] = v;
    __syncthreads();
    for (int d = 1; d < 256; d <<= 1) {
        int u = (t >= d) ? sd[t - d] : 0;
        __syncthreads();
        sd[t] += u;
        __syncthreads();
    }
    if (t < nb) bsums[t] = sd[t] - v;
}

__global__ __launch_bounds__(256) void scan3_kernel(int* __restrict__ off,
                                                    int* __restrict__ cursor,
                                                    const int* __restrict__ bsums,
                                                    int n, int total) {
    const int t = threadIdx.x;
    const int base = blockIdx.x * SCAN_CHUNK + t * 4;
    const int add = bsums[blockIdx.x];
#pragma unroll
    for (int j = 0; j < 4; ++j) {
        const int idx = base + j;
        if (idx < n) {
            const int v = off[idx] + add;
            off[idx] = v;
            cursor[idx] = v;
        }
    }
    if (blockIdx.x == 0 && t == 0) off[n] = total;
}

// ---------------- Ranged scatter with XCD affinity ----------------
// blockIdx = sr*(NXCD*SCHUNKS) + chunk*NXCD + xr ; range = sr*NXCD + xr.
// Consecutive blockIdx round-robin XCDs => all blocks of range r (fixed xr)
// run on ONE XCD: r's 0.8MB pairs window + cursors live in a single L2, so
// 64B lines accumulate all 8 pairs before writeback (kills cross-XCD
// partial-line eviction that kept round-3's fix at only -25%).
__global__ __launch_bounds__(256) void scatter_kernel(const int* __restrict__ src,
                                                      const int* __restrict__ dst,
                                                      const float* __restrict__ w,
                                                      int* __restrict__ cursor,
                                                      int2* __restrict__ pairs,
                                                      int E, int nodes_per_range) {
    const int xr = blockIdx.x % NXCD;
    const int rest = blockIdx.x / NXCD;
    const int chunk = rest % SCHUNKS;
    const int sr = rest / SCHUNKS;
    const int range = sr * NXCD + xr;
    const int r_lo = range * nodes_per_range;
    const int r_hi = r_lo + nodes_per_range;
    const int per_chunk = (E + SCHUNKS - 1) / SCHUNKS;
    const int start = chunk * per_chunk;
    const int end = min(E, start + per_chunk);
    for (int i = start + threadIdx.x; i < end; i += 256) {
        const int d = dst[i];
        if (d >= r_lo && d < r_hi) {
            const int pos = atomicAdd(&cursor[d], 1);
            int2 p;
            p.x = src[i];
            p.y = __float_as_int(w[i]);
            pairs[pos] = p;
        }
    }
}

// ---------------- Gather: out[n] = sum_e w_e * support[src_e] + B ----------------
// One 64-lane wave per node; lane covers 2 feats (float2). 8-deep batches:
// 8 broadcast pair loads then 8 independent row loads in flight per iter.
// Out-of-range slots get w=0 (row 0 read harmlessly) -> no tail code.
__global__ __launch_bounds__(256) void gather_kernel(const float* __restrict__ S,
                                                     const int* __restrict__ off,
                                                     const int2* __restrict__ pairs,
                                                     const float* __restrict__ B,
                                                     float* __restrict__ out, int n) {
    const int node = blockIdx.x * 4 + (threadIdx.x >> 6);
    const int lane = threadIdx.x & 63;
    if (node >= n) return;
    const int s = off[node];
    const int e = off[node + 1];
    const size_t fo = (size_t)lane * 2;
    float a0x = 0.f, a0y = 0.f, a1x = 0.f, a1y = 0.f;
    float a2x = 0.f, a2y = 0.f, a3x = 0.f, a3y = 0.f;
    for (int i = s; i < e; i += 8) {
        int2 p[8];
#pragma unroll
        for (int j = 0; j < 8; ++j) {
            p[j] = (i + j < e) ? pairs[i + j] : make_int2(0, 0);
        }
        float2 v[8];
#pragma unroll
        for (int j = 0; j < 8; ++j) {
            v[j] = *reinterpret_cast<const float2*>(&S[(size_t)p[j].x * OUT_F + fo]);
        }
        a0x += __int_as_float(p[0].y) * v[0].x; a0y += __int_as_float(p[0].y) * v[0].y;
        a1x += __int_as_float(p[1].y) * v[1].x; a1y += __int_as_float(p[1].y) * v[1].y;
        a2x += __int_as_float(p[2].y) * v[2].x; a2y += __int_as_float(p[2].y) * v[2].y;
        a3x += __int_as_float(p[3].y) * v[3].x; a3y += __int_as_float(p[3].y) * v[3].y;
        a0x += __int_as_float(p[4].y) * v[4].x; a0y += __int_as_float(p[4].y) * v[4].y;
        a1x += __int_as_float(p[5].y) * v[5].x; a1y += __int_as_float(p[5].y) * v[5].y;
        a2x += __int_as_float(p[6].y) * v[6].x; a2y += __int_as_float(p[6].y) * v[6].y;
        a3x += __int_as_float(p[7].y) * v[7].x; a3y += __int_as_float(p[7].y) * v[7].y;
    }
    const float2 b2 = *reinterpret_cast<const float2*>(&B[fo]);
    float2 o;
    o.x = (a0x + a1x) + (a2x + a3x) + b2.x;
    o.y = (a0y + a1y) + (a2y + a3y) + b2.y;
    *reinterpret_cast<float2*>(&out[(size_t)node * OUT_F + fo]) = o;
}

// ---------------- Fallback (small ws): direct f32 atomics ----------------
__global__ void init_out_kernel(float* __restrict__ out, const float* __restrict__ B, size_t n) {
    size_t i = (size_t)blockIdx.x * blockDim.x + threadIdx.x;
    const size_t stride = (size_t)gridDim.x * blockDim.x;
    for (; i < n; i += stride) out[i] = B[i & (OUT_F - 1)];
}

__global__ void atomic_scatter_kernel(const float* __restrict__ S, const int* __restrict__ src,
                                      const int* __restrict__ dst, const float* __restrict__ w,
                                      float* __restrict__ out, int E) {
    size_t i = (size_t)blockIdx.x * blockDim.x + threadIdx.x;
    const size_t stride = (size_t)gridDim.x * blockDim.x;
    const size_t total = (size_t)E * OUT_F;
    for (; i < total; i += stride) {
        const int e = (int)(i >> 7);
        const int f = (int)(i & 127);
        atomicAdd(&out[(size_t)dst[e] * OUT_F + f], w[e] * S[(size_t)src[e] * OUT_F + f]);
    }
}

extern "C" void kernel_launch(void* const* d_in, const int* in_sizes, int n_in,
                              void* d_out, int out_size, void* d_ws, size_t ws_size,
                              hipStream_t stream) {
    const float* X    = (const float*)d_in[0];
    const float* W    = (const float*)d_in[1];
    const float* B    = (const float*)d_in[2];
    const int*   esrc = (const int*)d_in[3];
    const int*   edst = (const int*)d_in[4];
    const float* ew   = (const float*)d_in[5];
    float* out = (float*)d_out;

    const int N = in_sizes[0] / IN_F;
    const int E = in_sizes[3];

    char* ws = (char*)d_ws;
    size_t cur = 0;
    auto carve = [&](size_t bytes) -> void* {
        void* p = ws + cur;
        cur = (cur + bytes + 255) & ~(size_t)255;
        return p;
    };
    float* support = (float*)carve((size_t)N * OUT_F * sizeof(float));
    int*   counts  = (int*)carve((size_t)N * sizeof(int));
    int*   offs    = (int*)carve((size_t)(N + 1) * sizeof(int));
    int*   cursor  = (int*)carve((size_t)N * sizeof(int));
    int*   bsums   = (int*)carve(1024 * sizeof(int));
    int2*  pairs   = (int2*)carve((size_t)E * sizeof(int2));
    const bool csr_ok = (cur <= ws_size);

    const int gemm_grid = (N + 63) / 64;
    gemm_kernel<<<gemm_grid, 256, 0, stream>>>(X, W, support, N);

    if (csr_ok) {
        hipMemsetAsync(counts, 0, (size_t)N * sizeof(int), stream);
        hist_kernel<<<2048, 256, 0, stream>>>(edst, counts, E);
        const int nb = (N + SCAN_CHUNK - 1) / SCAN_CHUNK;
        scan1_kernel<<<nb, 256, 0, stream>>>(counts, offs, bsums, N);
        scan2_kernel<<<1, 256, 0, stream>>>(bsums, nb);
        scan3_kernel<<<nb, 256, 0, stream>>>(offs, cursor, bsums, N, E);
        const int npr = (N + RANGES - 1) / RANGES;
        scatter_kernel<<<RANGES * SCHUNKS, 256, 0, stream>>>(esrc, edst, ew, cursor, pairs, E, npr);
        gather_kernel<<<(N + 3) / 4, 256, 0, stream>>>(support, offs, pairs, B, out, N);
    } else {
        init_out_kernel<<<2048, 256, 0, stream>>>(out, B, (size_t)N * OUT_F);
        atomic_scatter_kernel<<<4096, 256, 0, stream>>>(support, esrc, edst, ew, out, E);
    }
}

// Round 7
// 500.764 us; speedup vs baseline: 1.0447x; 1.0447x over previous
//
#include <hip/hip_runtime.h>
#include <cstddef>

#define IN_F 256
#define OUT_F 128
#define SCAN_CHUNK 1024
#define RANGES 8
#define SCHUNKS 512
#define NXCD 8

// ---------------- GEMM: support = X @ W  (fp32, vector FMA) ----------------
// BM=64 rows, BN=128 cols (=OUT_F), BK=32. 256 threads; each thread 8x4 outputs.
__global__ __launch_bounds__(256) void gemm_kernel(const float* __restrict__ X,
                                                   const float* __restrict__ W,
                                                   float* __restrict__ S,
                                                   int nrows) {
    __shared__ float Xs[32][68];    // [k][row], stride 68: b128-aligned (272B)
    __shared__ float Ws[32][128];   // [k][col]
    const int t = threadIdx.x;
    const int bm = blockIdx.x * 64;
    const int tr = (t >> 5) * 8;
    const int tc = (t & 31) * 4;
    float acc[8][4] = {};

    for (int kt = 0; kt < IN_F; kt += 32) {
#pragma unroll
        for (int l = 0; l < 2; ++l) {
            const int idx = t + l * 256;
            const int r = idx >> 3;
            const int k4 = idx & 7;
            int rr = bm + r; if (rr >= nrows) rr = nrows - 1;
            const float4 v = *reinterpret_cast<const float4*>(
                &X[(size_t)rr * IN_F + kt + k4 * 4]);
            Xs[k4 * 4 + 0][r] = v.x;
            Xs[k4 * 4 + 1][r] = v.y;
            Xs[k4 * 4 + 2][r] = v.z;
            Xs[k4 * 4 + 3][r] = v.w;
        }
#pragma unroll
        for (int l = 0; l < 4; ++l) {
            const int q = t + l * 256;
            const int k = q >> 5;
            const int c = (q & 31) * 4;
            *reinterpret_cast<float4*>(&Ws[k][c]) =
                *reinterpret_cast<const float4*>(&W[(size_t)(kt + k) * OUT_F + c]);
        }
        __syncthreads();
#pragma unroll 4
        for (int kk = 0; kk < 32; ++kk) {
            const float4 x0 = *reinterpret_cast<const float4*>(&Xs[kk][tr]);
            const float4 x1 = *reinterpret_cast<const float4*>(&Xs[kk][tr + 4]);
            const float4 wv = *reinterpret_cast<const float4*>(&Ws[kk][tc]);
            const float xr8[8] = {x0.x, x0.y, x0.z, x0.w, x1.x, x1.y, x1.z, x1.w};
#pragma unroll
            for (int j = 0; j < 8; ++j) {
                acc[j][0] += xr8[j] * wv.x;
                acc[j][1] += xr8[j] * wv.y;
                acc[j][2] += xr8[j] * wv.z;
                acc[j][3] += xr8[j] * wv.w;
            }
        }
        __syncthreads();
    }
#pragma unroll
    for (int j = 0; j < 8; ++j) {
        const int row = bm + tr + j;
        if (row < nrows) {
            *reinterpret_cast<float4*>(&S[(size_t)row * OUT_F + tc]) =
                make_float4(acc[j][0], acc[j][1], acc[j][2], acc[j][3]);
        }
    }
}

// ---------------- CSR build ----------------
__global__ void hist_kernel(const int* __restrict__ dst, int* __restrict__ counts, int E) {
    int i = blockIdx.x * blockDim.x + threadIdx.x;
    const int stride = gridDim.x * blockDim.x;
    for (; i < E; i += stride) atomicAdd(&counts[dst[i]], 1);
}

__global__ __launch_bounds__(256) void scan1_kernel(const int* __restrict__ counts,
                                                    int* __restrict__ off,
                                                    int* __restrict__ bsums, int n) {
    __shared__ int sd[256];
    const int t = threadIdx.x;
    const int base = blockIdx.x * SCAN_CHUNK + t * 4;
    int c[4]; int s = 0;
#pragma unroll
    for (int j = 0; j < 4; ++j) {
        c[j] = (base + j < n) ? counts[base + j] : 0;
        s += c[j];
    }
    sd[t] = s;
    __syncthreads();
    for (int d = 1; d < 256; d <<= 1) {
        int v = (t >= d) ? sd[t - d] : 0;
        __syncthreads();
        sd[t] += v;
        __syncthreads();
    }
    int run = sd[t] - s;
#pragma unroll
    for (int j = 0; j < 4; ++j) {
        if (base + j < n) off[base + j] = run;
        run += c[j];
    }
    if (t == 255) bsums[blockIdx.x] = sd[255];
}

__global__ __launch_bounds__(256) void scan2_kernel(int* __restrict__ bsums, int nb) {
    __shared__ int sd[256];
    const int t = threadIdx.x;
    const int v = (t < nb) ? bsums[t] : 0;
    sd[t] = v;
    __syncthreads();
    for (int d = 1; d < 256; d <<= 1) {
        int u = (t >= d) ? sd[t - d] : 0;
        __syncthreads();
        sd[t] += u;
        __syncthreads();
    }
    if (t < nb) bsums[t] = sd[t] - v;
}

__global__ __launch_bounds__(256) void scan3_kernel(int* __restrict__ off,
                                                    int* __restrict__ cursor,
                                                    const int* __restrict__ bsums,
                                                    int n, int total) {
    const int t = threadIdx.x;
    const int base = blockIdx.x * SCAN_CHUNK + t * 4;
    const int add = bsums[blockIdx.x];
#pragma unroll
    for (int j = 0; j < 4; ++j) {
        const int idx = base + j;
        if (idx < n) {
            const int v = off[idx] + add;
            off[idx] = v;
            cursor[idx] = v;
        }
    }
    if (blockIdx.x == 0 && t == 0) off[n] = total;
}

// ---------------- Ranged scatter (8 ranges, XCD-affine) ----------------
// blockIdx = chunk*NXCD + xr ; range = xr. Consecutive blockIdx round-robin
// XCDs => all blocks of range r run on one XCD: r's 1.6MB pairs window +
// cursors live in a single L2 (lines fill before writeback). RANGES=8 halves
// the read-amplification vs 16 (dst re-reads: 51MB; masked src/w: ~90MB).
__global__ __launch_bounds__(256) void scatter_kernel(const int* __restrict__ src,
                                                      const int* __restrict__ dst,
                                                      const float* __restrict__ w,
                                                      int* __restrict__ cursor,
                                                      int2* __restrict__ pairs,
                                                      int E, int nodes_per_range) {
    const int range = blockIdx.x % NXCD;
    const int chunk = blockIdx.x / NXCD;
    const int r_lo = range * nodes_per_range;
    const int r_hi = r_lo + nodes_per_range;
    const int per_chunk = (E + SCHUNKS - 1) / SCHUNKS;
    const int start = chunk * per_chunk;
    const int end = min(E, start + per_chunk);
    for (int i = start + threadIdx.x; i < end; i += 256) {
        const int d = dst[i];
        if (d >= r_lo && d < r_hi) {
            const int pos = atomicAdd(&cursor[d], 1);
            int2 p;
            p.x = src[i];
            p.y = __float_as_int(w[i]);
            pairs[pos] = p;
        }
    }
}

// ---------------- Gather: out[n] = sum_e w_e * support[src_e] + B ----------------
// One 64-lane wave per node; lane covers 2 feats (float2 => 512B/row/instr).
// 8-deep UNpredicated main loop (8 pair loads, then 8 independent row loads
// in flight), explicit 4-step + 1-step tails. No per-slot compares (round-5's
// predication cost 17%).
__global__ __launch_bounds__(256) void gather_kernel(const float* __restrict__ S,
                                                     const int* __restrict__ off,
                                                     const int2* __restrict__ pairs,
                                                     const float* __restrict__ B,
                                                     float* __restrict__ out, int n) {
    const int node = blockIdx.x * 4 + (threadIdx.x >> 6);
    const int lane = threadIdx.x & 63;
    if (node >= n) return;
    const int s = off[node];
    const int e = off[node + 1];
    const size_t fo = (size_t)lane * 2;
    float a0x = 0.f, a0y = 0.f, a1x = 0.f, a1y = 0.f;
    float a2x = 0.f, a2y = 0.f, a3x = 0.f, a3y = 0.f;
    int i = s;
    for (; i + 8 <= e; i += 8) {
        const int2 p0 = pairs[i];
        const int2 p1 = pairs[i + 1];
        const int2 p2 = pairs[i + 2];
        const int2 p3 = pairs[i + 3];
        const int2 p4 = pairs[i + 4];
        const int2 p5 = pairs[i + 5];
        const int2 p6 = pairs[i + 6];
        const int2 p7 = pairs[i + 7];
        const float2 v0 = *reinterpret_cast<const float2*>(&S[(size_t)p0.x * OUT_F + fo]);
        const float2 v1 = *reinterpret_cast<const float2*>(&S[(size_t)p1.x * OUT_F + fo]);
        const float2 v2 = *reinterpret_cast<const float2*>(&S[(size_t)p2.x * OUT_F + fo]);
        const float2 v3 = *reinterpret_cast<const float2*>(&S[(size_t)p3.x * OUT_F + fo]);
        const float2 v4 = *reinterpret_cast<const float2*>(&S[(size_t)p4.x * OUT_F + fo]);
        const float2 v5 = *reinterpret_cast<const float2*>(&S[(size_t)p5.x * OUT_F + fo]);
        const float2 v6 = *reinterpret_cast<const float2*>(&S[(size_t)p6.x * OUT_F + fo]);
        const float2 v7 = *reinterpret_cast<const float2*>(&S[(size_t)p7.x * OUT_F + fo]);
        a0x += __int_as_float(p0.y) * v0.x; a0y += __int_as_float(p0.y) * v0.y;
        a1x += __int_as_float(p1.y) * v1.x; a1y += __int_as_float(p1.y) * v1.y;
        a2x += __int_as_float(p2.y) * v2.x; a2y += __int_as_float(p2.y) * v2.y;
        a3x += __int_as_float(p3.y) * v3.x; a3y += __int_as_float(p3.y) * v3.y;
        a0x += __int_as_float(p4.y) * v4.x; a0y += __int_as_float(p4.y) * v4.y;
        a1x += __int_as_float(p5.y) * v5.x; a1y += __int_as_float(p5.y) * v5.y;
        a2x += __int_as_float(p6.y) * v6.x; a2y += __int_as_float(p6.y) * v6.y;
        a3x += __int_as_float(p7.y) * v7.x; a3y += __int_as_float(p7.y) * v7.y;
    }
    if (i + 4 <= e) {
        const int2 p0 = pairs[i];
        const int2 p1 = pairs[i + 1];
        const int2 p2 = pairs[i + 2];
        const int2 p3 = pairs[i + 3];
        const float2 v0 = *reinterpret_cast<const float2*>(&S[(size_t)p0.x * OUT_F + fo]);
        const float2 v1 = *reinterpret_cast<const float2*>(&S[(size_t)p1.x * OUT_F + fo]);
        const float2 v2 = *reinterpret_cast<const float2*>(&S[(size_t)p2.x * OUT_F + fo]);
        const float2 v3 = *reinterpret_cast<const float2*>(&S[(size_t)p3.x * OUT_F + fo]);
        a0x += __int_as_float(p0.y) * v0.x; a0y += __int_as_float(p0.y) * v0.y;
        a1x += __int_as_float(p1.y) * v1.x; a1y += __int_as_float(p1.y) * v1.y;
        a2x += __int_as_float(p2.y) * v2.x; a2y += __int_as_float(p2.y) * v2.y;
        a3x += __int_as_float(p3.y) * v3.x; a3y += __int_as_float(p3.y) * v3.y;
        i += 4;
    }
    for (; i < e; ++i) {
        const int2 p = pairs[i];
        const float2 v = *reinterpret_cast<const float2*>(&S[(size_t)p.x * OUT_F + fo]);
        const float wv = __int_as_float(p.y);
        a0x += wv * v.x; a0y += wv * v.y;
    }
    const float2 b2 = *reinterpret_cast<const float2*>(&B[fo]);
    float2 o;
    o.x = (a0x + a1x) + (a2x + a3x) + b2.x;
    o.y = (a0y + a1y) + (a2y + a3y) + b2.y;
    *reinterpret_cast<float2*>(&out[(size_t)node * OUT_F + fo]) = o;
}

// ---------------- Fallback (small ws): direct f32 atomics ----------------
__global__ void init_out_kernel(float* __restrict__ out, const float* __restrict__ B, size_t n) {
    size_t i = (size_t)blockIdx.x * blockDim.x + threadIdx.x;
    const size_t stride = (size_t)gridDim.x * blockDim.x;
    for (; i < n; i += stride) out[i] = B[i & (OUT_F - 1)];
}

__global__ void atomic_scatter_kernel(const float* __restrict__ S, const int* __restrict__ src,
                                      const int* __restrict__ dst, const float* __restrict__ w,
                                      float* __restrict__ out, int E) {
    size_t i = (size_t)blockIdx.x * blockDim.x + threadIdx.x;
    const size_t stride = (size_t)gridDim.x * blockDim.x;
    const size_t total = (size_t)E * OUT_F;
    for (; i < total; i += stride) {
        const int e = (int)(i >> 7);
        const int f = (int)(i & 127);
        atomicAdd(&out[(size_t)dst[e] * OUT_F + f], w[e] * S[(size_t)src[e] * OUT_F + f]);
    }
}

extern "C" void kernel_launch(void* const* d_in, const int* in_sizes, int n_in,
                              void* d_out, int out_size, void* d_ws, size_t ws_size,
                              hipStream_t stream) {
    const float* X    = (const float*)d_in[0];
    const float* W    = (const float*)d_in[1];
    const float* B    = (const float*)d_in[2];
    const int*   esrc = (const int*)d_in[3];
    const int*   edst = (const int*)d_in[4];
    const float* ew   = (const float*)d_in[5];
    float* out = (float*)d_out;

    const int N = in_sizes[0] / IN_F;
    const int E = in_sizes[3];

    char* ws = (char*)d_ws;
    size_t cur = 0;
    auto carve = [&](size_t bytes) -> void* {
        void* p = ws + cur;
        cur = (cur + bytes + 255) & ~(size_t)255;
        return p;
    };
    float* support = (float*)carve((size_t)N * OUT_F * sizeof(float));
    int*   counts  = (int*)carve((size_t)N * sizeof(int));
    int*   offs    = (int*)carve((size_t)(N + 1) * sizeof(int));
    int*   cursor  = (int*)carve((size_t)N * sizeof(int));
    int*   bsums   = (int*)carve(1024 * sizeof(int));
    int2*  pairs   = (int2*)carve((size_t)E * sizeof(int2));
    const bool csr_ok = (cur <= ws_size);

    const int gemm_grid = (N + 63) / 64;
    gemm_kernel<<<gemm_grid, 256, 0, stream>>>(X, W, support, N);

    if (csr_ok) {
        hipMemsetAsync(counts, 0, (size_t)N * sizeof(int), stream);
        hist_kernel<<<2048, 256, 0, stream>>>(edst, counts, E);
        const int nb = (N + SCAN_CHUNK - 1) / SCAN_CHUNK;
        scan1_kernel<<<nb, 256, 0, stream>>>(counts, offs, bsums, N);
        scan2_kernel<<<1, 256, 0, stream>>>(bsums, nb);
        scan3_kernel<<<nb, 256, 0, stream>>>(offs, cursor, bsums, N, E);
        const int npr = (N + RANGES - 1) / RANGES;
        scatter_kernel<<<SCHUNKS * NXCD, 256, 0, stream>>>(esrc, edst, ew, cursor, pairs, E, npr);
        gather_kernel<<<(N + 3) / 4, 256, 0, stream>>>(support, offs, pairs, B, out, N);
    } else {
        init_out_kernel<<<2048, 256, 0, stream>>>(out, B, (size_t)N * OUT_F);
        atomic_scatter_kernel<<<4096, 256, 0, stream>>>(support, esrc, edst, ew, out, E);
    }
}